// Round 20
// baseline (996.201 us; speedup 1.0000x reference)
//
#include <hip/hip_runtime.h>
#include <hip/hip_bf16.h>

#define BATCH 64
#define HID 512
#define EMB 256
#define VOCAB 32000
#define G4 2048   // 4*HID

typedef __attribute__((ext_vector_type(8))) short short8;
typedef __attribute__((ext_vector_type(4))) float f32x4;
typedef __attribute__((ext_vector_type(4))) unsigned short ush4;

// ---------------- zero init ----------------
__global__ __launch_bounds__(256) void zero_kernel(float* p, int n){
    int i = blockIdx.x*256 + threadIdx.x;
    if (i < n) p[i] = 0.f;
}

// round-to-nearest-even fp32 -> bf16 bits
__device__ __forceinline__ unsigned short bf16_rne(float x){
    unsigned b = __float_as_uint(x);
    return (unsigned short)((b + 0x7fffu + ((b >> 16) & 1u)) >> 16);
}
__device__ __forceinline__ void split2(float x, unsigned short& h, unsigned short& l){
    h = bf16_rne(x);
    l = bf16_rne(x - __uint_as_float((unsigned)h << 16));
}

// ---------------- embedding gather (fp32, fallback path) ----------------
__global__ __launch_bounds__(256) void embed_kernel(const int* __restrict__ tok,
                                                    const float* __restrict__ emb,
                                                    float* __restrict__ out, int T){
    int i = blockIdx.x*256 + threadIdx.x;
    int n = T*BATCH*(EMB/4);
    if (i >= n) return;
    int e4 = i % (EMB/4);
    int tb = i / (EMB/4);
    int id = tok[tb];
    reinterpret_cast<float4*>(out)[(size_t)tb*(EMB/4) + e4] =
        reinterpret_cast<const float4*>(emb + (size_t)id*EMB)[e4];
}

// ---------------- embedding gather straight into bf16 hi/lo planes ----------------
__global__ __launch_bounds__(256) void embed_plane_kernel(const int* __restrict__ tok,
                                                          const float* __restrict__ emb,
                                                          unsigned short* __restrict__ hi,
                                                          unsigned short* __restrict__ lo, int T){
    int i = blockIdx.x*256 + threadIdx.x;
    int n = T*BATCH*(EMB/4);
    if (i >= n) return;
    int e4 = i % (EMB/4);
    int tb = i / (EMB/4);
    int id = tok[tb];
    f32x4 v = reinterpret_cast<const f32x4*>(emb + (size_t)id*EMB)[e4];
    ush4 h, l;
    #pragma unroll
    for (int j = 0; j < 4; j++){ unsigned short a,b; split2(v[j], a, b); h[j]=a; l[j]=b; }
    reinterpret_cast<ush4*>(hi)[(size_t)tb*(EMB/4) + e4] = h;
    reinterpret_cast<ush4*>(lo)[(size_t)tb*(EMB/4) + e4] = l;
}

// ---------------- ONE batched split for all weights ----------------
__global__ __launch_bounds__(256) void split_all_kernel(
    const float* __restrict__ outW, unsigned short* __restrict__ Whi,
    const float* __restrict__ w0, unsigned short* __restrict__ w0h, unsigned short* __restrict__ w0l,
    const float* __restrict__ w1, unsigned short* __restrict__ w1h, unsigned short* __restrict__ w1l,
    const float* __restrict__ w2, unsigned short* __restrict__ w2h, unsigned short* __restrict__ w2l,
    const float* __restrict__ w3, unsigned short* __restrict__ w3h, unsigned short* __restrict__ w3l)
{
    int i = blockIdx.x*256 + threadIdx.x;
    if (i < 4096000){
        f32x4 v = reinterpret_cast<const f32x4*>(outW)[i];
        ush4 h;
        #pragma unroll
        for (int j = 0; j < 4; j++) h[j] = bf16_rne(v[j]);
        reinterpret_cast<ush4*>(Whi)[i] = h;
        return;
    }
    i -= 4096000;
    const float* src; unsigned short* dh; unsigned short* dl;
    if (i < 131072){ src = w0; dh = w0h; dl = w0l; }
    else if (i < 131072+262144){ i -= 131072; src = w1; dh = w1h; dl = w1l; }
    else if (i < 131072+262144+131072){ i -= 131072+262144; src = w2; dh = w2h; dl = w2l; }
    else if (i < 131072+262144+131072+262144){ i -= 131072+262144+131072; src = w3; dh = w3h; dl = w3l; }
    else return;
    f32x4 v = reinterpret_cast<const f32x4*>(src)[i];
    ush4 h, l;
    #pragma unroll
    for (int j = 0; j < 4; j++){ unsigned short a,b; split2(v[j], a, b); h[j]=a; l[j]=b; }
    reinterpret_cast<ush4*>(dh)[i] = h;
    reinterpret_cast<ush4*>(dl)[i] = l;
}

// ---------------- MFMA split GEMM, fp32 inputs (fallback only) ----------------
template<int KDIM, int NDIM>
__global__ __launch_bounds__(256) void gemm_mfma_split(
    const float* __restrict__ A, const float* __restrict__ B,
    const float* __restrict__ bias, float* __restrict__ C, int M)
{
    constexpr int LS = 40;
    __shared__ unsigned short Ah[128*LS], Al[128*LS], Bh[128*LS], Bl[128*LS];
    const int n0 = blockIdx.x*128, m0 = blockIdx.y*128;
    const int tid  = threadIdx.x;
    const int lane = tid & 63, wid = tid >> 6;
    const int wm = wid >> 1, wn = wid & 1;
    const int srow = tid >> 1, sk = (tid & 1)*16;
    f32x4 acc[4][4] = {};

    for (int k0 = 0; k0 < KDIM; k0 += 32){
        __syncthreads();
        {
            int ar = m0 + srow;
            float xv[16];
            if (ar < M){
                const float4* ap = reinterpret_cast<const float4*>(A + (size_t)ar*KDIM + k0 + sk);
                #pragma unroll
                for (int q = 0; q < 4; q++){
                    float4 v = ap[q];
                    xv[q*4+0]=v.x; xv[q*4+1]=v.y; xv[q*4+2]=v.z; xv[q*4+3]=v.w;
                }
            } else {
                #pragma unroll
                for (int q = 0; q < 16; q++) xv[q] = 0.f;
            }
            #pragma unroll
            for (int q = 0; q < 16; q++){
                unsigned short h,l; split2(xv[q], h, l);
                Ah[srow*LS + sk + q] = h;
                Al[srow*LS + sk + q] = l;
            }
        }
        {
            int br = n0 + srow;
            const float4* bp = reinterpret_cast<const float4*>(B + (size_t)br*KDIM + k0 + sk);
            #pragma unroll
            for (int q = 0; q < 4; q++){
                float4 v = bp[q];
                float xs[4] = {v.x, v.y, v.z, v.w};
                #pragma unroll
                for (int j = 0; j < 4; j++){
                    unsigned short h,l; split2(xs[j], h, l);
                    Bh[srow*LS + sk + q*4 + j] = h;
                    Bl[srow*LS + sk + q*4 + j] = l;
                }
            }
        }
        __syncthreads();
        const int fr = lane & 15, fk = (lane >> 4)*8;
        short8 a_h[4], a_l[4], b_h[4], b_l[4];
        #pragma unroll
        for (int mi = 0; mi < 4; mi++){
            int row = wm*64 + mi*16 + fr;
            a_h[mi] = *reinterpret_cast<const short8*>(&Ah[row*LS + fk]);
            a_l[mi] = *reinterpret_cast<const short8*>(&Al[row*LS + fk]);
        }
        #pragma unroll
        for (int nj = 0; nj < 4; nj++){
            int rowb = wn*64 + nj*16 + fr;
            b_h[nj] = *reinterpret_cast<const short8*>(&Bh[rowb*LS + fk]);
            b_l[nj] = *reinterpret_cast<const short8*>(&Bl[rowb*LS + fk]);
        }
        #pragma unroll
        for (int mi = 0; mi < 4; mi++)
            #pragma unroll
            for (int nj = 0; nj < 4; nj++){
                acc[mi][nj] = __builtin_amdgcn_mfma_f32_16x16x32_bf16(a_h[mi], b_h[nj], acc[mi][nj], 0,0,0);
                acc[mi][nj] = __builtin_amdgcn_mfma_f32_16x16x32_bf16(a_h[mi], b_l[nj], acc[mi][nj], 0,0,0);
                acc[mi][nj] = __builtin_amdgcn_mfma_f32_16x16x32_bf16(a_l[mi], b_h[nj], acc[mi][nj], 0,0,0);
            }
    }
    const int fr = lane & 15, fq = lane >> 4;
    #pragma unroll
    for (int nj = 0; nj < 4; nj++){
        int col = n0 + wn*64 + nj*16 + fr;
        float bv = bias[col];
        #pragma unroll
        for (int mi = 0; mi < 4; mi++){
            int rbase = m0 + wm*64 + mi*16 + fq*4;
            #pragma unroll
            for (int j = 0; j < 4; j++){
                int row = rbase + j;
                if (row < M)
                    __builtin_nontemporal_store(acc[mi][nj][j] + bv, &C[(size_t)row*NDIM + col]);
            }
        }
    }
}

// ---- global_load_lds width-16 helper (size must be a literal) ----
__device__ __forceinline__ void gll16(const unsigned short* g, unsigned short* l){
    __builtin_amdgcn_global_load_lds(
        (const __attribute__((address_space(1))) unsigned int*)g,
        (__attribute__((address_space(3))) unsigned int*)l, 16, 0, 0);
}

// ---------------- plane GEMM 128x128, 3-pass body ----------------
template<int KDIM, int NDIM, int NTN>
__device__ __forceinline__ void gemm_gll_body(
    const unsigned short* __restrict__ Ahi, const unsigned short* __restrict__ Alo,
    const unsigned short* __restrict__ Bhi, const unsigned short* __restrict__ Blo,
    const float* __restrict__ bias, float* __restrict__ C, int M,
    int bid_raw, int total)
{
    __shared__ unsigned short P[4][128*32];
    const int q = total >> 3, r8 = total & 7;
    const int xcd = bid_raw & 7, idx = bid_raw >> 3;
    const int lid = (xcd < r8 ? xcd*(q+1) : r8*(q+1) + (xcd - r8)*q) + idx;
    const int m0 = (lid / NTN)*128, n0 = (lid % NTN)*128;

    const int tid  = threadIdx.x;
    const int lane = tid & 63, wid = tid >> 6;
    const int wm = wid >> 1, wn = wid & 1;

    const unsigned short* gsrc = (wid == 0) ? Ahi : (wid == 1) ? Alo
                               : (wid == 2) ? Bhi : Blo;
    const int row0 = (wid < 2) ? m0 : n0;
    const unsigned short* gbase = gsrc + (size_t)(row0 + (lane >> 2))*KDIM
                                       + 8*((lane & 3) ^ ((lane >> 3) & 3));
    unsigned short* lbase = &P[wid][0];

    f32x4 acc[4][4] = {};

    for (int k0 = 0; k0 < KDIM; k0 += 32){
        __syncthreads();
        #pragma unroll
        for (int i = 0; i < 8; i++)
            gll16(gbase + k0 + (size_t)i*16*KDIM, lbase + i*512);
        __syncthreads();

        const int fr = lane & 15, fkq = lane >> 4;
        const int swz = 8*(fkq ^ ((fr >> 1) & 3));
        short8 a_h[4], a_l[4], b_h[4], b_l[4];
        #pragma unroll
        for (int mi = 0; mi < 4; mi++){
            int row = wm*64 + mi*16 + fr;
            a_h[mi] = *reinterpret_cast<const short8*>(&P[0][row*32 + swz]);
            a_l[mi] = *reinterpret_cast<const short8*>(&P[1][row*32 + swz]);
        }
        #pragma unroll
        for (int nj = 0; nj < 4; nj++){
            int row = wn*64 + nj*16 + fr;
            b_h[nj] = *reinterpret_cast<const short8*>(&P[2][row*32 + swz]);
            b_l[nj] = *reinterpret_cast<const short8*>(&P[3][row*32 + swz]);
        }
        #pragma unroll
        for (int mi = 0; mi < 4; mi++)
            #pragma unroll
            for (int nj = 0; nj < 4; nj++){
                acc[mi][nj] = __builtin_amdgcn_mfma_f32_16x16x32_bf16(a_h[mi], b_h[nj], acc[mi][nj], 0,0,0);
                acc[mi][nj] = __builtin_amdgcn_mfma_f32_16x16x32_bf16(a_l[mi], b_h[nj], acc[mi][nj], 0,0,0);
                acc[mi][nj] = __builtin_amdgcn_mfma_f32_16x16x32_bf16(a_h[mi], b_l[nj], acc[mi][nj], 0,0,0);
            }
    }
    const int fr = lane & 15, fq = lane >> 4;
    #pragma unroll
    for (int nj = 0; nj < 4; nj++){
        int col = n0 + wn*64 + nj*16 + fr;
        float bv = bias[col];
        #pragma unroll
        for (int mi = 0; mi < 4; mi++){
            int rbase = m0 + wm*64 + mi*16 + fq*4;
            #pragma unroll
            for (int j = 0; j < 4; j++){
                int row = rbase + j;
                if (row < M)
                    __builtin_nontemporal_store(acc[mi][nj][j] + bv, &C[(size_t)row*NDIM + col]);
            }
        }
    }
}

template<int KDIM, int NDIM, int NTN>
__global__ __launch_bounds__(256) void gemm_planes_gll(
    const unsigned short* Ahi, const unsigned short* Alo,
    const unsigned short* Bhi, const unsigned short* Blo,
    const float* bias, float* C, int M)
{
    gemm_gll_body<KDIM, NDIM, NTN>(Ahi, Alo, Bhi, Blo, bias, C, M,
                                   blockIdx.x, gridDim.x);
}

// ---------------- final GEMM body: 256x128, 1-pass bf16, 8 waves, progress-gated ----------------
// gprog[bc] (8 words) = steps completed+drained by bc-group. m-tile j needs
// gprog >= min(4j+4, T) before its A rows (time steps 4j..4j+3) are valid.
template<int KDIM, int NDIM, int NTN>
__device__ __forceinline__ void gemm_final_body(
    const unsigned short* __restrict__ Ahi,
    const unsigned short* __restrict__ Bhi,
    const float* __restrict__ bias, float* __restrict__ C, int M,
    int bid, int total, unsigned* __restrict__ gprog, int T)
{
    __shared__ unsigned short Ah[256*32];   // 16 KB
    __shared__ unsigned short Bh[128*32];   // 8 KB
    const int q = total >> 3, r8 = total & 7;
    const int xcd = bid & 7, idx = bid >> 3;
    const int lid = (xcd < r8 ? xcd*(q+1) : r8*(q+1) + (xcd - r8)*q) + idx;
    const int m0 = (lid / NTN)*256, n0 = (lid % NTN)*128;

    const int tid  = threadIdx.x;
    const int lane = tid & 63, wid = tid >> 6;
    const int wm = wid >> 1, wn = wid & 1;

    // gate on producer progress (wave 0 polls, bounded)
    if (gprog){
        int thresh = 4*(lid / NTN) + 4;
        if (thresh > T) thresh = T;
        if (tid < 64){
            unsigned spins = 0; bool done = false;
            while (!done && spins < (1u<<14)){
                unsigned v = (unsigned)thresh;
                if (tid < 8)
                    v = __hip_atomic_load(&gprog[tid], __ATOMIC_RELAXED, __HIP_MEMORY_SCOPE_AGENT);
                done = (bool)__all((int)(v >= (unsigned)thresh));
                spins++;
                if (!done) __builtin_amdgcn_s_sleep(8);
            }
        }
        __syncthreads();
    }

    const bool stager = (wid < 6);
    const unsigned short* gsrc = (wid < 4) ? Ahi : Bhi;
    const int grow0 = (wid < 4) ? (m0 + wid*64) : (n0 + (wid - 4)*64);
    const unsigned short* gbase = gsrc + (size_t)(grow0 + (lane >> 2))*KDIM
                                       + 8*((lane & 3) ^ ((lane >> 3) & 3));
    unsigned short* lbase = (wid < 4) ? (Ah + wid*64*32) : (Bh + (wid - 4)*64*32);

    f32x4 acc[4][4] = {};

    for (int k0 = 0; k0 < KDIM; k0 += 32){
        __syncthreads();
        if (stager){
            #pragma unroll
            for (int i = 0; i < 4; i++)
                gll16(gbase + k0 + (size_t)i*16*KDIM, lbase + i*512);
        }
        __syncthreads();

        const int fr = lane & 15, fkq = lane >> 4;
        const int swz = 8*(fkq ^ ((fr >> 1) & 3));
        short8 a_h[4], b_h[4];
        #pragma unroll
        for (int nj = 0; nj < 4; nj++){
            int row = wn*64 + nj*16 + fr;
            b_h[nj] = *reinterpret_cast<const short8*>(&Bh[row*32 + swz]);
        }
        #pragma unroll
        for (int mi = 0; mi < 4; mi++){
            int row = wm*64 + mi*16 + fr;
            a_h[mi] = *reinterpret_cast<const short8*>(&Ah[row*32 + swz]);
        }
        #pragma unroll
        for (int mi = 0; mi < 4; mi++)
            #pragma unroll
            for (int nj = 0; nj < 4; nj++)
                acc[mi][nj] = __builtin_amdgcn_mfma_f32_16x16x32_bf16(a_h[mi], b_h[nj], acc[mi][nj], 0,0,0);
    }
    const int fr = lane & 15, fq = lane >> 4;
    #pragma unroll
    for (int nj = 0; nj < 4; nj++){
        int col = n0 + wn*64 + nj*16 + fr;
        float bv = bias[col];
        #pragma unroll
        for (int mi = 0; mi < 4; mi++){
            int rbase = m0 + wm*64 + mi*16 + fq*4;
            #pragma unroll
            for (int j = 0; j < 4; j++){
                int row = rbase + j;
                if (row < M)
                    __builtin_nontemporal_store(acc[mi][nj][j] + bv, &C[(size_t)row*NDIM + col]);
            }
        }
    }
}

// standalone final GEMM (used when ws too small for the fused path)
template<int KDIM, int NDIM, int NTN>
__global__ __launch_bounds__(512) void gemm_planes_256w8(
    const unsigned short* Ahi, const unsigned short* Bhi,
    const float* bias, float* C, int M)
{
    gemm_final_body<KDIM, NDIM, NTN>(Ahi, Bhi, bias, C, M,
                                     blockIdx.x, gridDim.x, nullptr, 0);
}

// ---------------- persistent LSTM body, 4-wave / 256-thread (unchanged, proven) ----------------
__device__ __forceinline__ void lstm_body(
    const float* __restrict__ Xp, const float* __restrict__ Whh,
    const float* __restrict__ hinit, const float* __restrict__ cinit,
    float* __restrict__ ys, float* __restrict__ cfin,
    int T, unsigned* __restrict__ flagbase, int bx,
    unsigned short* __restrict__ phi, unsigned short* __restrict__ plo)
{
    constexpr int WS = 520;
    __shared__ unsigned short hH[8*WS], hL[8*WS];
    __shared__ __align__(16) float red[4*544 + 128];
    __shared__ unsigned short zbuf[8];

    const int bc  = bx & 7, hc = bx >> 3;
    const int hid0 = hc*16;
    const int tid = threadIdx.x;
    const int lane = tid & 63, kc = tid >> 6;
    const int fr = lane & 15, fkq = lane >> 4;
    unsigned* myflag = flagbase + (size_t)(bc*32 + hc)*16;

    if (tid < 8) zbuf[tid] = 0;

    short8 ah[4][4], al[4][4];
    #pragma unroll
    for (int m = 0; m < 4; m++){
        const float* wr = Whh + (size_t)(m*HID + hid0 + fr)*HID;
        #pragma unroll
        for (int s = 0; s < 4; s++){
            int k0 = kc*128 + s*32 + fkq*8;
            f32x4 v0 = *reinterpret_cast<const f32x4*>(wr + k0);
            f32x4 v1 = *reinterpret_cast<const f32x4*>(wr + k0 + 4);
            short8 h8, l8;
            float xv[8] = {v0[0],v0[1],v0[2],v0[3],v1[0],v1[1],v1[2],v1[3]};
            #pragma unroll
            for (int j = 0; j < 8; j++){
                unsigned short hh, ll; split2(xv[j], hh, ll);
                h8[j] = (short)hh; l8[j] = (short)ll;
            }
            ah[m][s] = h8; al[m][s] = l8;
        }
    }

    const int ub = tid >> 4;
    const int uh = tid & 15;
    float creg = 0.f;
    if (tid < 128) creg = cinit[(size_t)(bc*8 + ub)*HID + hid0 + uh];

    const size_t hbase = (size_t)bc*8*HID;
    const float* xprow = Xp + (size_t)(bc*8 + ub)*G4 + hid0 + uh;

    float xn0=0.f, xn1=0.f, xn2=0.f, xn3=0.f;
    if (tid < 128){
        const float* xpr = xprow;
        xn0 = xpr[0]; xn1 = xpr[512]; xn2 = xpr[1024]; xn3 = xpr[1536];
    }

    for (int t = 0; t < T; t++){
        {
            const f32x4* hsrc = reinterpret_cast<const f32x4*>(
                (t == 0) ? (hinit + hbase) : (ys + (size_t)(t-1)*BATCH*HID + hbase));
            #pragma unroll
            for (int j = 0; j < 4; j++){
                int fidx = tid + j*256;
                f32x4 v = hsrc[fidx];
                int e   = fidx*4;
                int row = e >> 9, col = e & 511;
                ush4 h, l;
                #pragma unroll
                for (int qq = 0; qq < 4; qq++){ unsigned short a,b; split2(v[qq], a, b); h[qq]=a; l[qq]=b; }
                *reinterpret_cast<ush4*>(&hH[row*WS + col]) = h;
                *reinterpret_cast<ush4*>(&hL[row*WS + col]) = l;
            }
        }
        __syncthreads();

        {
            f32x4 acc4[4] = {};
            const bool breal = fr < 8;
            #pragma unroll
            for (int s = 0; s < 4; s++){
                int k0 = kc*128 + s*32 + fkq*8;
                short8 bh = breal ? *reinterpret_cast<const short8*>(&hH[fr*WS + k0])
                                  : *reinterpret_cast<const short8*>(zbuf);
                short8 bl = breal ? *reinterpret_cast<const short8*>(&hL[fr*WS + k0])
                                  : *reinterpret_cast<const short8*>(zbuf);
                #pragma unroll
                for (int m = 0; m < 4; m++){
                    acc4[m] = __builtin_amdgcn_mfma_f32_16x16x32_bf16(ah[m][s], bh, acc4[m], 0,0,0);
                    acc4[m] = __builtin_amdgcn_mfma_f32_16x16x32_bf16(ah[m][s], bl, acc4[m], 0,0,0);
                    acc4[m] = __builtin_amdgcn_mfma_f32_16x16x32_bf16(al[m][s], bh, acc4[m], 0,0,0);
                }
            }
            const int b = lane & 15;
            if (b < 8){
                #pragma unroll
                for (int m = 0; m < 4; m++)
                    *reinterpret_cast<f32x4*>(&red[kc*544 + b*68 + m*16 + (lane >> 4)*4]) = acc4[m];
            }
        }
        __syncthreads();

        if (tid < 64){
            #pragma unroll
            for (int b = 0; b < 8; b++)
                red[b*68 + tid] = red[b*68 + tid] + red[544 + b*68 + tid]
                               + red[1088 + b*68 + tid] + red[1632 + b*68 + tid];
        }
        __syncthreads();

        if (tid < 128){
            float gi = red[ub*68 + 0*16 + uh] + xn0;
            float gf = red[ub*68 + 1*16 + uh] + xn1;
            float gg = red[ub*68 + 2*16 + uh] + xn2;
            float go = red[ub*68 + 3*16 + uh] + xn3;
            float si = 1.f/(1.f + expf(-gi));
            float sf = 1.f/(1.f + expf(-gf));
            float so = 1.f/(1.f + expf(-go));
            float tg = tanhf(gg);
            float c = sf*creg + si*tg;
            creg = c;
            float hval = so * tanhf(c);
            red[2176 + tid] = hval;
            if (phi){
                unsigned short hh, ll; split2(hval, hh, ll);
                size_t poff = (size_t)t*BATCH*HID + (size_t)(bc*8 + ub)*HID + hid0 + uh;
                phi[poff] = hh; plo[poff] = ll;
            }
            if (t < T-1){
                const float* xpr = xprow + (size_t)(t+1)*BATCH*G4;
                xn0 = xpr[0]; xn1 = xpr[512]; xn2 = xpr[1024]; xn3 = xpr[1536];
            }
        }
        __syncthreads();

        if (tid < 64){
            if (tid < 32){
                f32x4 v = *reinterpret_cast<const f32x4*>(&red[2176 + tid*4]);
                const f32x4* addr = reinterpret_cast<const f32x4*>(
                    ys + (size_t)t*BATCH*HID
                       + (size_t)(bc*8 + (tid >> 2))*HID + hid0 + (tid & 3)*4);
                asm volatile("global_store_dwordx4 %0, %1, off sc0 sc1"
                             :: "v"(addr), "v"(v) : "memory");
            }
            if (t < T-1){
                asm volatile("s_waitcnt vmcnt(0)" ::: "memory");
                if (tid == 0)
                    __hip_atomic_store(myflag, (unsigned)(t+1),
                                       __ATOMIC_RELAXED, __HIP_MEMORY_SCOPE_AGENT);
                const unsigned tgt = (unsigned)(t+1);
                unsigned* fp = flagbase + (size_t)(bc*32 + (tid & 31))*16;
                unsigned spins = 0;
                bool done = false;
                while (!done && spins < (1u<<20)){
                    unsigned v = tgt;
                    if (tid < 32)
                        v = __hip_atomic_load(fp, __ATOMIC_RELAXED, __HIP_MEMORY_SCOPE_AGENT);
                    done = (bool)__all((int)(v >= tgt));
                    spins++;
                }
            }
        }
        __syncthreads();
    }

    if (tid < 128)
        cfin[(size_t)(bc*8 + ub)*HID + hid0 + uh] = creg;
}

__global__ __launch_bounds__(256, 2) void lstm_layer_k(
    const float* Xp, const float* Whh, const float* hinit, const float* cinit,
    float* ys, float* cfin, int T, unsigned* flagbase,
    unsigned short* phi, unsigned short* plo)
{
    lstm_body(Xp, Whh, hinit, cinit, ys, cfin, T, flagbase, blockIdx.x, phi, plo);
}

__global__ __launch_bounds__(256, 2) void lstm_dual_k(
    const float* Xp0, const float* Whh0, const float* hi0, const float* ci0,
    float* ys0, float* cf0, int T0, unsigned* fl0,
    unsigned short* phi0, unsigned short* plo0,
    const float* Xp1, const float* Whh1, const float* hi1, const float* ci1,
    float* ys1, float* cf1, int T1, unsigned* fl1,
    unsigned short* phi1, unsigned short* plo1)
{
    const int role = blockIdx.x >> 8;
    const int bx = blockIdx.x & 255;
    if (role == 0)
        lstm_body(Xp0, Whh0, hi0, ci0, ys0, cf0, T0, fl0, bx, phi0, plo0);
    else
        lstm_body(Xp1, Whh1, hi1, ci1, ys1, cf1, T1, fl1, bx, phi1, plo1);
}

// ---- fused: encL0 LSTM (blocks 0..255) + independent decL0-Xp GEMM ----
__global__ __launch_bounds__(256, 2) void lstm_gemm_k(
    const float* Xp, const float* Whh, const float* hinit, const float* cinit,
    float* ys, float* cfin, int T, unsigned* flagbase,
    unsigned short* phi, unsigned short* plo,
    const unsigned short* gAhi, const unsigned short* gAlo,
    const unsigned short* gBhi, const unsigned short* gBlo,
    const float* gbias, float* gC, int gM, int gTotal)
{
    if ((int)blockIdx.x < 256)
        lstm_body(Xp, Whh, hinit, cinit, ys, cfin, T, flagbase, blockIdx.x, phi, plo);
    else
        gemm_gll_body<EMB, G4, 16>(gAhi, gAlo, gBhi, gBlo, gbias, gC, gM,
                                   blockIdx.x - 256, gTotal);
}

// ---------------- 8-wave / 512-thread LSTM body (for the decL1+final fusion) ----------------
// K split over 8 waves (64 cols each). Plane output (phi/plo) emitted by wave 0 as
// sc0/sc1 8B stores, drained by the vmcnt(0) BEFORE the flag store -> flag value t+1
// implies h AND planes of step t are at the coherence point. Flag published EVERY
// step (incl. last). hc==0 blocks publish per-bc group progress to gprog after each
// group barrier (and T after a final group poll).
__device__ __forceinline__ void lstm_body8(
    const float* __restrict__ Xp, const float* __restrict__ Whh,
    const float* __restrict__ hinit, const float* __restrict__ cinit,
    float* __restrict__ ys, float* __restrict__ cfin,
    int T, unsigned* __restrict__ flagbase, int bx,
    unsigned short* __restrict__ phi, unsigned short* __restrict__ plo,
    unsigned* __restrict__ gprog)
{
    constexpr int WS = 520;
    __shared__ unsigned short hH[8*WS], hL[8*WS];
    __shared__ __align__(16) float red[8*544 + 128];
    __shared__ unsigned short zbuf[8];

    const int bc = bx & 7, hc = bx >> 3;
    const int hid0 = hc*16;
    const int tid = threadIdx.x;           // 0..511
    const int lane = tid & 63, kc = tid >> 6;   // kc 0..7
    const int fr = lane & 15, fkq = lane >> 4;
    unsigned* myflag = flagbase + (size_t)(bc*32 + hc)*16;

    if (tid < 8) zbuf[tid] = 0;

    short8 ah[4][2], al[4][2];
    #pragma unroll
    for (int m = 0; m < 4; m++){
        const float* wr = Whh + (size_t)(m*HID + hid0 + fr)*HID;
        #pragma unroll
        for (int s = 0; s < 2; s++){
            int k0 = kc*64 + s*32 + fkq*8;
            f32x4 v0 = *reinterpret_cast<const f32x4*>(wr + k0);
            f32x4 v1 = *reinterpret_cast<const f32x4*>(wr + k0 + 4);
            short8 h8, l8;
            float xv[8] = {v0[0],v0[1],v0[2],v0[3],v1[0],v1[1],v1[2],v1[3]};
            #pragma unroll
            for (int j = 0; j < 8; j++){
                unsigned short hh, ll; split2(xv[j], hh, ll);
                h8[j] = (short)hh; l8[j] = (short)ll;
            }
            ah[m][s] = h8; al[m][s] = l8;
        }
    }

    const int ub = tid >> 4;
    const int uh = tid & 15;
    float creg = 0.f;
    if (tid < 128) creg = cinit[(size_t)(bc*8 + ub)*HID + hid0 + uh];

    const size_t hbase = (size_t)bc*8*HID;
    const float* xprow = Xp + (size_t)(bc*8 + ub)*G4 + hid0 + uh;

    float xn0=0.f, xn1=0.f, xn2=0.f, xn3=0.f;
    if (tid < 128){
        const float* xpr = xprow;
        xn0 = xpr[0]; xn1 = xpr[512]; xn2 = xpr[1024]; xn3 = xpr[1536];
    }

    for (int t = 0; t < T; t++){
        {
            const f32x4* hsrc = reinterpret_cast<const f32x4*>(
                (t == 0) ? (hinit + hbase) : (ys + (size_t)(t-1)*BATCH*HID + hbase));
            #pragma unroll
            for (int j = 0; j < 2; j++){
                int fidx = tid + j*512;
                f32x4 v = hsrc[fidx];
                int e   = fidx*4;
                int row = e >> 9, col = e & 511;
                ush4 h, l;
                #pragma unroll
                for (int qq = 0; qq < 4; qq++){ unsigned short a,b; split2(v[qq], a, b); h[qq]=a; l[qq]=b; }
                *reinterpret_cast<ush4*>(&hH[row*WS + col]) = h;
                *reinterpret_cast<ush4*>(&hL[row*WS + col]) = l;
            }
        }
        __syncthreads();

        {
            f32x4 acc4[4] = {};
            const bool breal = fr < 8;
            #pragma unroll
            for (int s = 0; s < 2; s++){
                int k0 = kc*64 + s*32 + fkq*8;
                short8 bh = breal ? *reinterpret_cast<const short8*>(&hH[fr*WS + k0])
                                  : *reinterpret_cast<const short8*>(zbuf);
                short8 bl = breal ? *reinterpret_cast<const short8*>(&hL[fr*WS + k0])
                                  : *reinterpret_cast<const short8*>(zbuf);
                #pragma unroll
                for (int m = 0; m < 4; m++){
                    acc4[m] = __builtin_amdgcn_mfma_f32_16x16x32_bf16(ah[m][s], bh, acc4[m], 0,0,0);
                    acc4[m] = __builtin_amdgcn_mfma_f32_16x16x32_bf16(ah[m][s], bl, acc4[m], 0,0,0);
                    acc4[m] = __builtin_amdgcn_mfma_f32_16x16x32_bf16(al[m][s], bh, acc4[m], 0,0,0);
                }
            }
            const int b = lane & 15;
            if (b < 8){
                #pragma unroll
                for (int m = 0; m < 4; m++)
                    *reinterpret_cast<f32x4*>(&red[kc*544 + b*68 + m*16 + (lane >> 4)*4]) = acc4[m];
            }
        }
        __syncthreads();

        if (tid < 64){
            #pragma unroll
            for (int b = 0; b < 8; b++){
                float v = red[b*68 + tid];
                #pragma unroll
                for (int s = 1; s < 8; s++) v += red[s*544 + b*68 + tid];
                red[b*68 + tid] = v;
            }
        }
        __syncthreads();

        if (tid < 128){
            float gi = red[ub*68 + 0*16 + uh] + xn0;
            float gf = red[ub*68 + 1*16 + uh] + xn1;
            float gg = red[ub*68 + 2*16 + uh] + xn2;
            float go = red[ub*68 + 3*16 + uh] + xn3;
            float si = 1.f/(1.f + expf(-gi));
            float sf = 1.f/(1.f + expf(-gf));
            float so = 1.f/(1.f + expf(-go));
            float tg = tanhf(gg);
            float c = sf*creg + si*tg;
            creg = c;
            red[4352 + tid] = so * tanhf(c);
            if (t < T-1){
                const float* xpr = xprow + (size_t)(t+1)*BATCH*G4;
                xn0 = xpr[0]; xn1 = xpr[512]; xn2 = xpr[1024]; xn3 = xpr[1536];
            }
        }
        __syncthreads();

        if (tid < 64){
            if (tid < 32){
                f32x4 v = *reinterpret_cast<const f32x4*>(&red[4352 + tid*4]);
                size_t eoff = (size_t)t*BATCH*HID
                            + (size_t)(bc*8 + (tid >> 2))*HID + hid0 + (tid & 3)*4;
                const f32x4* addr = reinterpret_cast<const f32x4*>(ys + eoff);
                asm volatile("global_store_dwordx4 %0, %1, off sc0 sc1"
                             :: "v"(addr), "v"(v) : "memory");
                if (phi){
                    ush4 hh, ll;
                    #pragma unroll
                    for (int j = 0; j < 4; j++){ unsigned short a,b; split2(v[j], a, b); hh[j]=a; ll[j]=b; }
                    const ush4* pa = reinterpret_cast<const ush4*>(phi + eoff);
                    const ush4* pb = reinterpret_cast<const ush4*>(plo + eoff);
                    asm volatile("global_store_dwordx2 %0, %1, off sc0 sc1"
                                 :: "v"(pa), "v"(hh) : "memory");
                    asm volatile("global_store_dwordx2 %0, %1, off sc0 sc1"
                                 :: "v"(pb), "v"(ll) : "memory");
                }
            }
            // drain h+planes, publish flag EVERY step
            asm volatile("s_waitcnt vmcnt(0)" ::: "memory");
            if (tid == 0)
                __hip_atomic_store(myflag, (unsigned)(t+1),
                                   __ATOMIC_RELAXED, __HIP_MEMORY_SCOPE_AGENT);
            if (t < T-1){
                const unsigned tgt = (unsigned)(t+1);
                unsigned* fp = flagbase + (size_t)(bc*32 + (tid & 31))*16;
                unsigned spins = 0;
                bool done = false;
                while (!done && spins < (1u<<20)){
                    unsigned v = tgt;
                    if (tid < 32)
                        v = __hip_atomic_load(fp, __ATOMIC_RELAXED, __HIP_MEMORY_SCOPE_AGENT);
                    done = (bool)__all((int)(v >= tgt));
                    spins++;
                }
                if (gprog && hc == 0 && tid == 0)
                    __hip_atomic_store(&gprog[bc], tgt,
                                       __ATOMIC_RELAXED, __HIP_MEMORY_SCOPE_AGENT);
            }
        }
        __syncthreads();
    }

    if (tid < 128)
        cfin[(size_t)(bc*8 + ub)*HID + hid0 + uh] = creg;

    // publish completion (all group members drained their last step)
    if (gprog && hc == 0 && tid < 64){
        const unsigned tgt = (unsigned)T;
        unsigned* fp = flagbase + (size_t)(bc*32 + (tid & 31))*16;
        unsigned spins = 0;
        bool done = false;
        while (!done && spins < (1u<<20)){
            unsigned v = tgt;
            if (tid < 32)
                v = __hip_atomic_load(fp, __ATOMIC_RELAXED, __HIP_MEMORY_SCOPE_AGENT);
            done = (bool)__all((int)(v >= tgt));
            spins++;
        }
        if (tid == 0)
            __hip_atomic_store(&gprog[bc], tgt,
                               __ATOMIC_RELAXED, __HIP_MEMORY_SCOPE_AGENT);
    }
}

// ---- fused: decL1 LSTM (blocks 0..255, 8-wave) + progress-gated final GEMM ----
__global__ __launch_bounds__(512, 2) void lstm_final_k(
    const float* Xp, const float* Whh, const float* hinit, const float* cinit,
    float* ys, float* cfin, int T, unsigned* flagbase,
    unsigned short* phi, unsigned short* plo, unsigned* gprog,
    const unsigned short* gA, const unsigned short* gB,
    const float* gbias, float* gC, int gM, int gTotal)
{
    if ((int)blockIdx.x < 256)
        lstm_body8(Xp, Whh, hinit, cinit, ys, cfin, T, flagbase, blockIdx.x,
                   phi, plo, gprog);
    else
        gemm_final_body<HID, VOCAB, 250>(gA, gB, gbias, gC, gM,
                                         blockIdx.x - 256, gTotal, gprog, T);
}

extern "C" void kernel_launch(void* const* d_in, const int* in_sizes, int n_in,
                              void* d_out, int out_size, void* d_ws, size_t ws_size,
                              hipStream_t stream) {
    const int*   src      = (const int*)  d_in[0];
    const int*   trg      = (const int*)  d_in[1];
    const float* enc_emb  = (const float*)d_in[2];
    const float* enc_Wih0 = (const float*)d_in[3];
    const float* enc_Whh0 = (const float*)d_in[4];
    const float* enc_b0   = (const float*)d_in[5];
    const float* enc_Wih1 = (const float*)d_in[6];
    const float* enc_Whh1 = (const float*)d_in[7];
    const float* enc_b1   = (const float*)d_in[8];
    const float* dec_emb  = (const float*)d_in[9];
    const float* dec_Wih0 = (const float*)d_in[10];
    const float* dec_Whh0 = (const float*)d_in[11];
    const float* dec_b0   = (const float*)d_in[12];
    const float* dec_Wih1 = (const float*)d_in[13];
    const float* dec_Whh1 = (const float*)d_in[14];
    const float* dec_b1   = (const float*)d_in[15];
    const float* out_W    = (const float*)d_in[16];
    const float* out_b    = (const float*)d_in[17];

    // Big transient scratch in d_out; all dead before the final GEMM's C writes begin
    // (in the fused path, decL1's Xp lives in d_ws since C writes overlap d_out).
    float* ob = (float*)d_out;
    float* Xp   = ob;                         // [3200,2048]
    float* xe   = ob + (size_t)6553600;       // fp32 fallback only
    float* xd   = ob + (size_t)7372800;       // fp32 fallback only
    float* eys0 = ob + (size_t)8175616;       // [50*64,512]
    float* eys1 = ob + (size_t)9814016;       // [50*64,512]
    float* dys0 = ob + (size_t)11452416;      // [49*64,512]
    float* Xp2  = ob + (size_t)13058048;      // [3136,2048]

    float* ws = (float*)d_ws;
    float* dys1 = ws;                              // [49*64,512]
    float* c0   = ws + (size_t)1605632;
    float* c1   = ws + (size_t)1638400;
    float* hz   = ws + (size_t)1671168;            // [64,512] zeros; last 16 floats double as gprog
    unsigned* flags = (unsigned*)(ws + (size_t)1703936); // 16384 uints
    unsigned* gprog = ((unsigned*)(ws + (size_t)1703936)) - 16;  // hz tail (zeroed each launch)
    unsigned short* Whi = (unsigned short*)(ws + (size_t)1720320);
    unsigned short* Wlo = Whi + (size_t)16384000;  // unused
    unsigned short* Ahi = Wlo + (size_t)16384000;
    unsigned short* Alo = Ahi + (size_t)1703936;   // 3328*512
    unsigned short* eW0h = Alo  + (size_t)1703936;
    unsigned short* eW0l = eW0h + (size_t)524288;
    unsigned short* eW1h = eW0l + (size_t)524288;
    unsigned short* eW1l = eW1h + (size_t)1048576;
    unsigned short* dW0h = eW1l + (size_t)1048576;
    unsigned short* dW0l = dW0h + (size_t)524288;
    unsigned short* dW1h = dW0l + (size_t)524288;
    unsigned short* dW1l = dW1h + (size_t)1048576;
    unsigned short* XAh  = dW1l + (size_t)1048576;
    unsigned short* XAl  = XAh  + (size_t)1638400;
    const size_t end_xp = (size_t)1720320*4 +
        2*((size_t)16384000*2 + (size_t)1703936*2 + (size_t)524288*4 +
           (size_t)1048576*4 + (size_t)1638400*2);
    float* Xp3 = (float*)((char*)d_ws + end_xp);   // [3136,2048] decL1 Xp (fused path)
    const size_t end_fused = end_xp + (size_t)3136*2048*4;
    const bool xp_ok    = (ws_size >= end_xp);
    const bool fused_ok = (ws_size >= end_fused);

    // zero c0,c1,hz(+gprog tail) + flags
    {
        int n = 3*BATCH*HID + 4*4096;
        zero_kernel<<<(n+255)/256, 256, 0, stream>>>(c0, n);
    }

    if (xp_ok){
        split_all_kernel<<<(4882432 + 255)/256, 256, 0, stream>>>(
            out_W, Whi,
            enc_Wih0, eW0h, eW0l,  enc_Wih1, eW1h, eW1l,
            dec_Wih0, dW0h, dW0l,  dec_Wih1, dW1h, dW1l);
        embed_plane_kernel<<<(50*BATCH*(EMB/4)+255)/256, 256, 0, stream>>>(src, enc_emb, XAh, XAl, 50);
        embed_plane_kernel<<<(49*BATCH*(EMB/4)+255)/256, 256, 0, stream>>>(trg, dec_emb, Ahi, Alo, 49);
    } else {
        embed_kernel<<<(50*BATCH*(EMB/4)+255)/256, 256, 0, stream>>>(src, enc_emb, xe, 50);
        embed_kernel<<<(49*BATCH*(EMB/4)+255)/256, 256, 0, stream>>>(trg, dec_emb, xd, 49);
    }

    dim3 xgrid(G4/128, 25);   // fallback grid

    // ---- encoder layer 0 Xp GEMM ----
    if (xp_ok)
        gemm_planes_gll<EMB, G4, 16><<<400, 256, 0, stream>>>(XAh, XAl, eW0h, eW0l, enc_b0, Xp, 3200);
    else
        gemm_mfma_split<EMB, G4><<<xgrid, 256, 0, stream>>>(xe, enc_Wih0, enc_b0, Xp, 3200);

    // ---- FUSED: encL0 LSTM + decL0-Xp GEMM ----
    if (xp_ok){
        lstm_gemm_k<<<656, 256, 0, stream>>>(
            Xp, enc_Whh0, hz, hz, eys0, c0, 50, flags + 0, XAh, XAl,
            Ahi, Alo, dW0h, dW0l, dec_b0, Xp2, 3136, 400);
    } else {
        lstm_layer_k<<<256, 256, 0, stream>>>(Xp, enc_Whh0, hz, hz, eys0, c0, 50, flags + 0,
                                              nullptr, nullptr);
        gemm_mfma_split<EMB, G4><<<xgrid, 256, 0, stream>>>(xd, dec_Wih0, dec_b0, Xp2, 3136);
    }

    // ---- encoder layer 1 Xp GEMM ----
    if (xp_ok)
        gemm_planes_gll<HID, G4, 16><<<400, 256, 0, stream>>>(XAh, XAl, eW1h, eW1l, enc_b1, Xp, 3200);
    else
        gemm_mfma_split<HID, G4><<<xgrid, 256, 0, stream>>>(eys0, enc_Wih1, enc_b1, Xp, 3200);

    // ---- encoder layer 1 AND decoder layer 0 concurrently ----
    lstm_dual_k<<<512, 256, 0, stream>>>(
        Xp,  enc_Whh1, hz,                          hz, eys1, c1, 50, flags + 4096,  nullptr, nullptr,
        Xp2, dec_Whh0, eys0 + (size_t)49*BATCH*HID, c0, dys0, c0, 49, flags + 8192,
        xp_ok ? XAh : nullptr, XAl);

    // ---- decoder layer 1 Xp GEMM (into Xp3 when fused; Xp otherwise) ----
    float* XpD1 = fused_ok ? Xp3 : Xp;
    if (xp_ok)
        gemm_planes_gll<HID, G4, 16><<<400, 256, 0, stream>>>(XAh, XAl, dW1h, dW1l, dec_b1, XpD1, 3136);
    else
        gemm_mfma_split<HID, G4><<<xgrid, 256, 0, stream>>>(dys0, dec_Wih1, dec_b1, XpD1, 3136);

    // ---- decoder layer 1 + final projection ----
    if (fused_ok){
        // producer-consumer fused: decL1 (8-wave) + progress-gated 256x128 final GEMM
        lstm_final_k<<<256 + 3250, 512, 0, stream>>>(
            Xp3, dec_Whh1, eys1 + (size_t)49*BATCH*HID, c1, dys1, c1, 49, flags + 12288,
            Ahi, Alo, gprog,
            Ahi, Whi, out_b, (float*)d_out, 3136, 3250);
    } else if (xp_ok){
        lstm_layer_k<<<256, 256, 0, stream>>>(XpD1, dec_Whh1, eys1 + (size_t)49*BATCH*HID, c1,
                                              dys1, c1, 49, flags + 12288, Ahi, Alo);
        gemm_planes_256w8<HID, VOCAB, 250><<<13*250, 512, 0, stream>>>(
            Ahi, Whi, out_b, (float*)d_out, 3136);
    } else {
        lstm_layer_k<<<256, 256, 0, stream>>>(XpD1, dec_Whh1, eys1 + (size_t)49*BATCH*HID, c1,
                                              dys1, c1, 49, flags + 12288, nullptr, nullptr);
        gemm_mfma_split<HID, VOCAB><<<dim3(VOCAB/128, 25), 256, 0, stream>>>(
            dys1, out_W, out_b, (float*)d_out, 3136);
    }
}

// Round 21
// 945.233 us; speedup vs baseline: 1.0539x; 1.0539x over previous
//
#include <hip/hip_runtime.h>
#include <hip/hip_bf16.h>

#define BATCH 64
#define HID 512
#define EMB 256
#define VOCAB 32000
#define G4 2048   // 4*HID

typedef __attribute__((ext_vector_type(8))) short short8;
typedef __attribute__((ext_vector_type(4))) float f32x4;
typedef __attribute__((ext_vector_type(4))) unsigned short ush4;

// ---------------- zero init ----------------
__global__ __launch_bounds__(256) void zero_kernel(float* p, int n){
    int i = blockIdx.x*256 + threadIdx.x;
    if (i < n) p[i] = 0.f;
}

// round-to-nearest-even fp32 -> bf16 bits
__device__ __forceinline__ unsigned short bf16_rne(float x){
    unsigned b = __float_as_uint(x);
    return (unsigned short)((b + 0x7fffu + ((b >> 16) & 1u)) >> 16);
}
__device__ __forceinline__ void split2(float x, unsigned short& h, unsigned short& l){
    h = bf16_rne(x);
    l = bf16_rne(x - __uint_as_float((unsigned)h << 16));
}

// ---------------- embedding gather (fp32, fallback path) ----------------
__global__ __launch_bounds__(256) void embed_kernel(const int* __restrict__ tok,
                                                    const float* __restrict__ emb,
                                                    float* __restrict__ out, int T){
    int i = blockIdx.x*256 + threadIdx.x;
    int n = T*BATCH*(EMB/4);
    if (i >= n) return;
    int e4 = i % (EMB/4);
    int tb = i / (EMB/4);
    int id = tok[tb];
    reinterpret_cast<float4*>(out)[(size_t)tb*(EMB/4) + e4] =
        reinterpret_cast<const float4*>(emb + (size_t)id*EMB)[e4];
}

// ---------------- embedding gather straight into bf16 hi/lo planes ----------------
__global__ __launch_bounds__(256) void embed_plane_kernel(const int* __restrict__ tok,
                                                          const float* __restrict__ emb,
                                                          unsigned short* __restrict__ hi,
                                                          unsigned short* __restrict__ lo, int T){
    int i = blockIdx.x*256 + threadIdx.x;
    int n = T*BATCH*(EMB/4);
    if (i >= n) return;
    int e4 = i % (EMB/4);
    int tb = i / (EMB/4);
    int id = tok[tb];
    f32x4 v = reinterpret_cast<const f32x4*>(emb + (size_t)id*EMB)[e4];
    ush4 h, l;
    #pragma unroll
    for (int j = 0; j < 4; j++){ unsigned short a,b; split2(v[j], a, b); h[j]=a; l[j]=b; }
    reinterpret_cast<ush4*>(hi)[(size_t)tb*(EMB/4) + e4] = h;
    reinterpret_cast<ush4*>(lo)[(size_t)tb*(EMB/4) + e4] = l;
}

// ---------------- ONE batched split for all weights ----------------
__global__ __launch_bounds__(256) void split_all_kernel(
    const float* __restrict__ outW, unsigned short* __restrict__ Whi,
    const float* __restrict__ w0, unsigned short* __restrict__ w0h, unsigned short* __restrict__ w0l,
    const float* __restrict__ w1, unsigned short* __restrict__ w1h, unsigned short* __restrict__ w1l,
    const float* __restrict__ w2, unsigned short* __restrict__ w2h, unsigned short* __restrict__ w2l,
    const float* __restrict__ w3, unsigned short* __restrict__ w3h, unsigned short* __restrict__ w3l)
{
    int i = blockIdx.x*256 + threadIdx.x;
    if (i < 4096000){
        f32x4 v = reinterpret_cast<const f32x4*>(outW)[i];
        ush4 h;
        #pragma unroll
        for (int j = 0; j < 4; j++) h[j] = bf16_rne(v[j]);
        reinterpret_cast<ush4*>(Whi)[i] = h;
        return;
    }
    i -= 4096000;
    const float* src; unsigned short* dh; unsigned short* dl;
    if (i < 131072){ src = w0; dh = w0h; dl = w0l; }
    else if (i < 131072+262144){ i -= 131072; src = w1; dh = w1h; dl = w1l; }
    else if (i < 131072+262144+131072){ i -= 131072+262144; src = w2; dh = w2h; dl = w2l; }
    else if (i < 131072+262144+131072+262144){ i -= 131072+262144+131072; src = w3; dh = w3h; dl = w3l; }
    else return;
    f32x4 v = reinterpret_cast<const f32x4*>(src)[i];
    ush4 h, l;
    #pragma unroll
    for (int j = 0; j < 4; j++){ unsigned short a,b; split2(v[j], a, b); h[j]=a; l[j]=b; }
    reinterpret_cast<ush4*>(dh)[i] = h;
    reinterpret_cast<ush4*>(dl)[i] = l;
}

// ---------------- MFMA split GEMM, fp32 inputs (fallback only) ----------------
template<int KDIM, int NDIM>
__global__ __launch_bounds__(256) void gemm_mfma_split(
    const float* __restrict__ A, const float* __restrict__ B,
    const float* __restrict__ bias, float* __restrict__ C, int M)
{
    constexpr int LS = 40;
    __shared__ unsigned short Ah[128*LS], Al[128*LS], Bh[128*LS], Bl[128*LS];
    const int n0 = blockIdx.x*128, m0 = blockIdx.y*128;
    const int tid  = threadIdx.x;
    const int lane = tid & 63, wid = tid >> 6;
    const int wm = wid >> 1, wn = wid & 1;
    const int srow = tid >> 1, sk = (tid & 1)*16;
    f32x4 acc[4][4] = {};

    for (int k0 = 0; k0 < KDIM; k0 += 32){
        __syncthreads();
        {
            int ar = m0 + srow;
            float xv[16];
            if (ar < M){
                const float4* ap = reinterpret_cast<const float4*>(A + (size_t)ar*KDIM + k0 + sk);
                #pragma unroll
                for (int q = 0; q < 4; q++){
                    float4 v = ap[q];
                    xv[q*4+0]=v.x; xv[q*4+1]=v.y; xv[q*4+2]=v.z; xv[q*4+3]=v.w;
                }
            } else {
                #pragma unroll
                for (int q = 0; q < 16; q++) xv[q] = 0.f;
            }
            #pragma unroll
            for (int q = 0; q < 16; q++){
                unsigned short h,l; split2(xv[q], h, l);
                Ah[srow*LS + sk + q] = h;
                Al[srow*LS + sk + q] = l;
            }
        }
        {
            int br = n0 + srow;
            const float4* bp = reinterpret_cast<const float4*>(B + (size_t)br*KDIM + k0 + sk);
            #pragma unroll
            for (int q = 0; q < 4; q++){
                float4 v = bp[q];
                float xs[4] = {v.x, v.y, v.z, v.w};
                #pragma unroll
                for (int j = 0; j < 4; j++){
                    unsigned short h,l; split2(xs[j], h, l);
                    Bh[srow*LS + sk + q*4 + j] = h;
                    Bl[srow*LS + sk + q*4 + j] = l;
                }
            }
        }
        __syncthreads();
        const int fr = lane & 15, fk = (lane >> 4)*8;
        short8 a_h[4], a_l[4], b_h[4], b_l[4];
        #pragma unroll
        for (int mi = 0; mi < 4; mi++){
            int row = wm*64 + mi*16 + fr;
            a_h[mi] = *reinterpret_cast<const short8*>(&Ah[row*LS + fk]);
            a_l[mi] = *reinterpret_cast<const short8*>(&Al[row*LS + fk]);
        }
        #pragma unroll
        for (int nj = 0; nj < 4; nj++){
            int rowb = wn*64 + nj*16 + fr;
            b_h[nj] = *reinterpret_cast<const short8*>(&Bh[rowb*LS + fk]);
            b_l[nj] = *reinterpret_cast<const short8*>(&Bl[rowb*LS + fk]);
        }
        #pragma unroll
        for (int mi = 0; mi < 4; mi++)
            #pragma unroll
            for (int nj = 0; nj < 4; nj++){
                acc[mi][nj] = __builtin_amdgcn_mfma_f32_16x16x32_bf16(a_h[mi], b_h[nj], acc[mi][nj], 0,0,0);
                acc[mi][nj] = __builtin_amdgcn_mfma_f32_16x16x32_bf16(a_h[mi], b_l[nj], acc[mi][nj], 0,0,0);
                acc[mi][nj] = __builtin_amdgcn_mfma_f32_16x16x32_bf16(a_l[mi], b_h[nj], acc[mi][nj], 0,0,0);
            }
    }
    const int fr = lane & 15, fq = lane >> 4;
    #pragma unroll
    for (int nj = 0; nj < 4; nj++){
        int col = n0 + wn*64 + nj*16 + fr;
        float bv = bias[col];
        #pragma unroll
        for (int mi = 0; mi < 4; mi++){
            int rbase = m0 + wm*64 + mi*16 + fq*4;
            #pragma unroll
            for (int j = 0; j < 4; j++){
                int row = rbase + j;
                if (row < M)
                    __builtin_nontemporal_store(acc[mi][nj][j] + bv, &C[(size_t)row*NDIM + col]);
            }
        }
    }
}

// ---- global_load_lds width-16 helper (size must be a literal) ----
__device__ __forceinline__ void gll16(const unsigned short* g, unsigned short* l){
    __builtin_amdgcn_global_load_lds(
        (const __attribute__((address_space(1))) unsigned int*)g,
        (__attribute__((address_space(3))) unsigned int*)l, 16, 0, 0);
}

// ---------------- plane GEMM 128x128, 3-pass body (callable from fused kernels) ----------------
template<int KDIM, int NDIM, int NTN>
__device__ __forceinline__ void gemm_gll_body(
    const unsigned short* __restrict__ Ahi, const unsigned short* __restrict__ Alo,
    const unsigned short* __restrict__ Bhi, const unsigned short* __restrict__ Blo,
    const float* __restrict__ bias, float* __restrict__ C, int M,
    int bid_raw, int total)
{
    __shared__ unsigned short P[4][128*32];
    const int q = total >> 3, r8 = total & 7;
    const int xcd = bid_raw & 7, idx = bid_raw >> 3;
    const int lid = (xcd < r8 ? xcd*(q+1) : r8*(q+1) + (xcd - r8)*q) + idx;
    const int m0 = (lid / NTN)*128, n0 = (lid % NTN)*128;

    const int tid  = threadIdx.x;
    const int lane = tid & 63, wid = tid >> 6;
    const int wm = wid >> 1, wn = wid & 1;

    const unsigned short* gsrc = (wid == 0) ? Ahi : (wid == 1) ? Alo
                               : (wid == 2) ? Bhi : Blo;
    const int row0 = (wid < 2) ? m0 : n0;
    const unsigned short* gbase = gsrc + (size_t)(row0 + (lane >> 2))*KDIM
                                       + 8*((lane & 3) ^ ((lane >> 3) & 3));
    unsigned short* lbase = &P[wid][0];

    f32x4 acc[4][4] = {};

    for (int k0 = 0; k0 < KDIM; k0 += 32){
        __syncthreads();
        #pragma unroll
        for (int i = 0; i < 8; i++)
            gll16(gbase + k0 + (size_t)i*16*KDIM, lbase + i*512);
        __syncthreads();

        const int fr = lane & 15, fkq = lane >> 4;
        const int swz = 8*(fkq ^ ((fr >> 1) & 3));
        short8 a_h[4], a_l[4], b_h[4], b_l[4];
        #pragma unroll
        for (int mi = 0; mi < 4; mi++){
            int row = wm*64 + mi*16 + fr;
            a_h[mi] = *reinterpret_cast<const short8*>(&P[0][row*32 + swz]);
            a_l[mi] = *reinterpret_cast<const short8*>(&P[1][row*32 + swz]);
        }
        #pragma unroll
        for (int nj = 0; nj < 4; nj++){
            int row = wn*64 + nj*16 + fr;
            b_h[nj] = *reinterpret_cast<const short8*>(&P[2][row*32 + swz]);
            b_l[nj] = *reinterpret_cast<const short8*>(&P[3][row*32 + swz]);
        }
        #pragma unroll
        for (int mi = 0; mi < 4; mi++)
            #pragma unroll
            for (int nj = 0; nj < 4; nj++){
                acc[mi][nj] = __builtin_amdgcn_mfma_f32_16x16x32_bf16(a_h[mi], b_h[nj], acc[mi][nj], 0,0,0);
                acc[mi][nj] = __builtin_amdgcn_mfma_f32_16x16x32_bf16(a_l[mi], b_h[nj], acc[mi][nj], 0,0,0);
                acc[mi][nj] = __builtin_amdgcn_mfma_f32_16x16x32_bf16(a_h[mi], b_l[nj], acc[mi][nj], 0,0,0);
            }
    }
    const int fr = lane & 15, fq = lane >> 4;
    #pragma unroll
    for (int nj = 0; nj < 4; nj++){
        int col = n0 + wn*64 + nj*16 + fr;
        float bv = bias[col];
        #pragma unroll
        for (int mi = 0; mi < 4; mi++){
            int rbase = m0 + wm*64 + mi*16 + fq*4;
            #pragma unroll
            for (int j = 0; j < 4; j++){
                int row = rbase + j;
                if (row < M)
                    __builtin_nontemporal_store(acc[mi][nj][j] + bv, &C[(size_t)row*NDIM + col]);
            }
        }
    }
}

template<int KDIM, int NDIM, int NTN>
__global__ __launch_bounds__(256) void gemm_planes_gll(
    const unsigned short* Ahi, const unsigned short* Alo,
    const unsigned short* Bhi, const unsigned short* Blo,
    const float* bias, float* C, int M)
{
    gemm_gll_body<KDIM, NDIM, NTN>(Ahi, Alo, Bhi, Blo, bias, C, M,
                                   blockIdx.x, gridDim.x);
}

// ---------------- plane GEMM 256x128, 1-pass bf16, 8 waves (final projection) ----------------
template<int KDIM, int NDIM, int NTN>
__global__ __launch_bounds__(512) void gemm_planes_256w8(
    const unsigned short* __restrict__ Ahi,
    const unsigned short* __restrict__ Bhi,
    const float* __restrict__ bias, float* __restrict__ C, int M)
{
    __shared__ unsigned short Ah[256*32];   // 16 KB
    __shared__ unsigned short Bh[128*32];   // 8 KB
    const int total = gridDim.x;
    const int q = total >> 3, r8 = total & 7;
    const int xcd = blockIdx.x & 7, idx = blockIdx.x >> 3;
    const int lid = (xcd < r8 ? xcd*(q+1) : r8*(q+1) + (xcd - r8)*q) + idx;
    const int m0 = (lid / NTN)*256, n0 = (lid % NTN)*128;

    const int tid  = threadIdx.x;
    const int lane = tid & 63, wid = tid >> 6;     // 0..7
    const int wm = wid >> 1, wn = wid & 1;         // 4m x 2n -> wave tile 64x64

    const bool stager = (wid < 6);
    const unsigned short* gsrc = (wid < 4) ? Ahi : Bhi;
    const int grow0 = (wid < 4) ? (m0 + wid*64) : (n0 + (wid - 4)*64);
    const unsigned short* gbase = gsrc + (size_t)(grow0 + (lane >> 2))*KDIM
                                       + 8*((lane & 3) ^ ((lane >> 3) & 3));
    unsigned short* lbase = (wid < 4) ? (Ah + wid*64*32) : (Bh + (wid - 4)*64*32);

    f32x4 acc[4][4] = {};

    for (int k0 = 0; k0 < KDIM; k0 += 32){
        __syncthreads();
        if (stager){
            #pragma unroll
            for (int i = 0; i < 4; i++)
                gll16(gbase + k0 + (size_t)i*16*KDIM, lbase + i*512);
        }
        __syncthreads();

        const int fr = lane & 15, fkq = lane >> 4;
        const int swz = 8*(fkq ^ ((fr >> 1) & 3));
        short8 a_h[4], b_h[4];
        #pragma unroll
        for (int nj = 0; nj < 4; nj++){
            int row = wn*64 + nj*16 + fr;
            b_h[nj] = *reinterpret_cast<const short8*>(&Bh[row*32 + swz]);
        }
        #pragma unroll
        for (int mi = 0; mi < 4; mi++){
            int row = wm*64 + mi*16 + fr;
            a_h[mi] = *reinterpret_cast<const short8*>(&Ah[row*32 + swz]);
        }
        #pragma unroll
        for (int mi = 0; mi < 4; mi++)
            #pragma unroll
            for (int nj = 0; nj < 4; nj++)
                acc[mi][nj] = __builtin_amdgcn_mfma_f32_16x16x32_bf16(a_h[mi], b_h[nj], acc[mi][nj], 0,0,0);
    }
    const int fr = lane & 15, fq = lane >> 4;
    #pragma unroll
    for (int nj = 0; nj < 4; nj++){
        int col = n0 + wn*64 + nj*16 + fr;
        float bv = bias[col];
        #pragma unroll
        for (int mi = 0; mi < 4; mi++){
            int rbase = m0 + wm*64 + mi*16 + fq*4;
            #pragma unroll
            for (int j = 0; j < 4; j++){
                int row = rbase + j;
                if (row < M)
                    __builtin_nontemporal_store(acc[mi][nj][j] + bv, &C[(size_t)row*NDIM + col]);
            }
        }
    }
}

// ---------------- persistent LSTM layer body (XCD-local groups, round-19 proven) ----------------
__device__ __forceinline__ void lstm_body(
    const float* __restrict__ Xp, const float* __restrict__ Whh,
    const float* __restrict__ hinit, const float* __restrict__ cinit,
    float* __restrict__ ys, float* __restrict__ cfin,
    int T, unsigned* __restrict__ flagbase, int bx,
    unsigned short* __restrict__ phi, unsigned short* __restrict__ plo)
{
    constexpr int WS = 520;
    __shared__ unsigned short hH[8*WS], hL[8*WS];
    __shared__ __align__(16) float red[4*544 + 128];
    __shared__ unsigned short zbuf[8];

    const int bc  = bx & 7, hc = bx >> 3;   // XCD-local groups
    const int hid0 = hc*16;
    const int tid = threadIdx.x;
    const int lane = tid & 63, kc = tid >> 6;
    const int fr = lane & 15, fkq = lane >> 4;
    unsigned* myflag = flagbase + (size_t)(bc*32 + hc)*16;

    if (tid < 8) zbuf[tid] = 0;

    short8 ah[4][4], al[4][4];
    #pragma unroll
    for (int m = 0; m < 4; m++){
        const float* wr = Whh + (size_t)(m*HID + hid0 + fr)*HID;
        #pragma unroll
        for (int s = 0; s < 4; s++){
            int k0 = kc*128 + s*32 + fkq*8;
            f32x4 v0 = *reinterpret_cast<const f32x4*>(wr + k0);
            f32x4 v1 = *reinterpret_cast<const f32x4*>(wr + k0 + 4);
            short8 h8, l8;
            float xv[8] = {v0[0],v0[1],v0[2],v0[3],v1[0],v1[1],v1[2],v1[3]};
            #pragma unroll
            for (int j = 0; j < 8; j++){
                unsigned short hh, ll; split2(xv[j], hh, ll);
                h8[j] = (short)hh; l8[j] = (short)ll;
            }
            ah[m][s] = h8; al[m][s] = l8;
        }
    }

    const int ub = tid >> 4;
    const int uh = tid & 15;
    float creg = 0.f;
    if (tid < 128) creg = cinit[(size_t)(bc*8 + ub)*HID + hid0 + uh];

    const size_t hbase = (size_t)bc*8*HID;
    const float* xprow = Xp + (size_t)(bc*8 + ub)*G4 + hid0 + uh;

    float xn0=0.f, xn1=0.f, xn2=0.f, xn3=0.f;
    if (tid < 128){
        const float* xpr = xprow;
        xn0 = xpr[0]; xn1 = xpr[512]; xn2 = xpr[1024]; xn3 = xpr[1536];
    }

    for (int t = 0; t < T; t++){
        {
            const f32x4* hsrc = reinterpret_cast<const f32x4*>(
                (t == 0) ? (hinit + hbase) : (ys + (size_t)(t-1)*BATCH*HID + hbase));
            #pragma unroll
            for (int j = 0; j < 4; j++){
                int fidx = tid + j*256;
                f32x4 v = hsrc[fidx];
                int e   = fidx*4;
                int row = e >> 9, col = e & 511;
                ush4 h, l;
                #pragma unroll
                for (int qq = 0; qq < 4; qq++){ unsigned short a,b; split2(v[qq], a, b); h[qq]=a; l[qq]=b; }
                *reinterpret_cast<ush4*>(&hH[row*WS + col]) = h;
                *reinterpret_cast<ush4*>(&hL[row*WS + col]) = l;
            }
        }
        __syncthreads();

        {
            f32x4 acc4[4] = {};
            const bool breal = fr < 8;
            #pragma unroll
            for (int s = 0; s < 4; s++){
                int k0 = kc*128 + s*32 + fkq*8;
                short8 bh = breal ? *reinterpret_cast<const short8*>(&hH[fr*WS + k0])
                                  : *reinterpret_cast<const short8*>(zbuf);
                short8 bl = breal ? *reinterpret_cast<const short8*>(&hL[fr*WS + k0])
                                  : *reinterpret_cast<const short8*>(zbuf);
                #pragma unroll
                for (int m = 0; m < 4; m++){
                    acc4[m] = __builtin_amdgcn_mfma_f32_16x16x32_bf16(ah[m][s], bh, acc4[m], 0,0,0);
                    acc4[m] = __builtin_amdgcn_mfma_f32_16x16x32_bf16(ah[m][s], bl, acc4[m], 0,0,0);
                    acc4[m] = __builtin_amdgcn_mfma_f32_16x16x32_bf16(al[m][s], bh, acc4[m], 0,0,0);
                }
            }
            const int b = lane & 15;
            if (b < 8){
                #pragma unroll
                for (int m = 0; m < 4; m++)
                    *reinterpret_cast<f32x4*>(&red[kc*544 + b*68 + m*16 + (lane >> 4)*4]) = acc4[m];
            }
        }
        __syncthreads();

        if (tid < 64){
            #pragma unroll
            for (int b = 0; b < 8; b++)
                red[b*68 + tid] = red[b*68 + tid] + red[544 + b*68 + tid]
                               + red[1088 + b*68 + tid] + red[1632 + b*68 + tid];
        }
        __syncthreads();

        if (tid < 128){
            float gi = red[ub*68 + 0*16 + uh] + xn0;
            float gf = red[ub*68 + 1*16 + uh] + xn1;
            float gg = red[ub*68 + 2*16 + uh] + xn2;
            float go = red[ub*68 + 3*16 + uh] + xn3;
            float si = 1.f/(1.f + expf(-gi));
            float sf = 1.f/(1.f + expf(-gf));
            float so = 1.f/(1.f + expf(-go));
            float tg = tanhf(gg);
            float c = sf*creg + si*tg;
            creg = c;
            float hval = so * tanhf(c);
            red[2176 + tid] = hval;
            if (phi){
                unsigned short hh, ll; split2(hval, hh, ll);
                size_t poff = (size_t)t*BATCH*HID + (size_t)(bc*8 + ub)*HID + hid0 + uh;
                phi[poff] = hh; plo[poff] = ll;
            }
            if (t < T-1){
                const float* xpr = xprow + (size_t)(t+1)*BATCH*G4;
                xn0 = xpr[0]; xn1 = xpr[512]; xn2 = xpr[1024]; xn3 = xpr[1536];
            }
        }
        __syncthreads();

        if (tid < 64){
            if (tid < 32){
                f32x4 v = *reinterpret_cast<const f32x4*>(&red[2176 + tid*4]);
                const f32x4* addr = reinterpret_cast<const f32x4*>(
                    ys + (size_t)t*BATCH*HID
                       + (size_t)(bc*8 + (tid >> 2))*HID + hid0 + (tid & 3)*4);
                asm volatile("global_store_dwordx4 %0, %1, off sc0 sc1"
                             :: "v"(addr), "v"(v) : "memory");
            }
            if (t < T-1){
                asm volatile("s_waitcnt vmcnt(0)" ::: "memory");
                if (tid == 0)
                    __hip_atomic_store(myflag, (unsigned)(t+1),
                                       __ATOMIC_RELAXED, __HIP_MEMORY_SCOPE_AGENT);
                const unsigned tgt = (unsigned)(t+1);
                unsigned* fp = flagbase + (size_t)(bc*32 + (tid & 31))*16;
                unsigned spins = 0;
                bool done = false;
                while (!done && spins < (1u<<20)){
                    unsigned v = tgt;
                    if (tid < 32)
                        v = __hip_atomic_load(fp, __ATOMIC_RELAXED, __HIP_MEMORY_SCOPE_AGENT);
                    done = (bool)__all((int)(v >= tgt));
                    spins++;
                }
            }
        }
        __syncthreads();
    }

    if (tid < 128)
        cfin[(size_t)(bc*8 + ub)*HID + hid0 + uh] = creg;
}

__global__ __launch_bounds__(256, 2) void lstm_layer_k(
    const float* Xp, const float* Whh, const float* hinit, const float* cinit,
    float* ys, float* cfin, int T, unsigned* flagbase,
    unsigned short* phi, unsigned short* plo)
{
    lstm_body(Xp, Whh, hinit, cinit, ys, cfin, T, flagbase, blockIdx.x, phi, plo);
}

__global__ __launch_bounds__(256, 2) void lstm_dual_k(
    const float* Xp0, const float* Whh0, const float* hi0, const float* ci0,
    float* ys0, float* cf0, int T0, unsigned* fl0,
    unsigned short* phi0, unsigned short* plo0,
    const float* Xp1, const float* Whh1, const float* hi1, const float* ci1,
    float* ys1, float* cf1, int T1, unsigned* fl1,
    unsigned short* phi1, unsigned short* plo1)
{
    const int role = blockIdx.x >> 8;
    const int bx = blockIdx.x & 255;
    if (role == 0)
        lstm_body(Xp0, Whh0, hi0, ci0, ys0, cf0, T0, fl0, bx, phi0, plo0);
    else
        lstm_body(Xp1, Whh1, hi1, ci1, ys1, cf1, T1, fl1, bx, phi1, plo1);
}

// ---- fused: encL0 LSTM (blocks 0..255) + independent decL0-Xp GEMM (blocks 256..655) ----
__global__ __launch_bounds__(256, 2) void lstm_gemm_k(
    const float* Xp, const float* Whh, const float* hinit, const float* cinit,
    float* ys, float* cfin, int T, unsigned* flagbase,
    unsigned short* phi, unsigned short* plo,
    const unsigned short* gAhi, const unsigned short* gAlo,
    const unsigned short* gBhi, const unsigned short* gBlo,
    const float* gbias, float* gC, int gM, int gTotal)
{
    if ((int)blockIdx.x < 256)
        lstm_body(Xp, Whh, hinit, cinit, ys, cfin, T, flagbase, blockIdx.x, phi, plo);
    else
        gemm_gll_body<EMB, G4, 16>(gAhi, gAlo, gBhi, gBlo, gbias, gC, gM,
                                   blockIdx.x - 256, gTotal);
}

extern "C" void kernel_launch(void* const* d_in, const int* in_sizes, int n_in,
                              void* d_out, int out_size, void* d_ws, size_t ws_size,
                              hipStream_t stream) {
    const int*   src      = (const int*)  d_in[0];
    const int*   trg      = (const int*)  d_in[1];
    const float* enc_emb  = (const float*)d_in[2];
    const float* enc_Wih0 = (const float*)d_in[3];
    const float* enc_Whh0 = (const float*)d_in[4];
    const float* enc_b0   = (const float*)d_in[5];
    const float* enc_Wih1 = (const float*)d_in[6];
    const float* enc_Whh1 = (const float*)d_in[7];
    const float* enc_b1   = (const float*)d_in[8];
    const float* dec_emb  = (const float*)d_in[9];
    const float* dec_Wih0 = (const float*)d_in[10];
    const float* dec_Whh0 = (const float*)d_in[11];
    const float* dec_b0   = (const float*)d_in[12];
    const float* dec_Wih1 = (const float*)d_in[13];
    const float* dec_Whh1 = (const float*)d_in[14];
    const float* dec_b1   = (const float*)d_in[15];
    const float* out_W    = (const float*)d_in[16];
    const float* out_b    = (const float*)d_in[17];

    // Big transient scratch in d_out (fp32, 100.35M elems); all dead before final GEMM.
    float* ob = (float*)d_out;
    float* Xp   = ob;                         // [3200,2048]
    float* xe   = ob + (size_t)6553600;       // fp32 fallback only
    float* xd   = ob + (size_t)7372800;       // fp32 fallback only
    float* eys0 = ob + (size_t)8175616;       // [50*64,512]
    float* eys1 = ob + (size_t)9814016;       // [50*64,512]
    float* dys0 = ob + (size_t)11452416;      // [49*64,512]
    float* Xp2  = ob + (size_t)13058048;      // [3136,2048]

    // d_ws layout (identical to rounds 17-19).
    float* ws = (float*)d_ws;
    float* dys1 = ws;                              // [49*64,512]
    float* c0   = ws + (size_t)1605632;
    float* c1   = ws + (size_t)1638400;
    float* hz   = ws + (size_t)1671168;
    unsigned* flags = (unsigned*)(ws + (size_t)1703936); // 16384 uints
    unsigned short* Whi = (unsigned short*)(ws + (size_t)1720320);
    unsigned short* Wlo = Whi + (size_t)16384000;  // unused (1-pass final)
    unsigned short* Ahi = Wlo + (size_t)16384000;
    unsigned short* Alo = Ahi + (size_t)1703936;   // 3328*512
    unsigned short* eW0h = Alo  + (size_t)1703936;
    unsigned short* eW0l = eW0h + (size_t)524288;
    unsigned short* eW1h = eW0l + (size_t)524288;
    unsigned short* eW1l = eW1h + (size_t)1048576;
    unsigned short* dW0h = eW1l + (size_t)1048576;
    unsigned short* dW0l = dW0h + (size_t)524288;
    unsigned short* dW1h = dW0l + (size_t)524288;
    unsigned short* dW1l = dW1h + (size_t)1048576;
    unsigned short* XAh  = dW1l + (size_t)1048576;
    unsigned short* XAl  = XAh  + (size_t)1638400;
    const size_t end_xp = (size_t)1720320*4 +
        2*((size_t)16384000*2 + (size_t)1703936*2 + (size_t)524288*4 +
           (size_t)1048576*4 + (size_t)1638400*2);
    const bool xp_ok = (ws_size >= end_xp);

    // zero c0,c1,hz + flags
    {
        int n = 3*BATCH*HID + 4*4096;
        zero_kernel<<<(n+255)/256, 256, 0, stream>>>(c0, n);
    }

    if (xp_ok){
        split_all_kernel<<<(4882432 + 255)/256, 256, 0, stream>>>(
            out_W, Whi,
            enc_Wih0, eW0h, eW0l,  enc_Wih1, eW1h, eW1l,
            dec_Wih0, dW0h, dW0l,  dec_Wih1, dW1h, dW1l);
        embed_plane_kernel<<<(50*BATCH*(EMB/4)+255)/256, 256, 0, stream>>>(src, enc_emb, XAh, XAl, 50);
        embed_plane_kernel<<<(49*BATCH*(EMB/4)+255)/256, 256, 0, stream>>>(trg, dec_emb, Ahi, Alo, 49);
    } else {
        embed_kernel<<<(50*BATCH*(EMB/4)+255)/256, 256, 0, stream>>>(src, enc_emb, xe, 50);
        embed_kernel<<<(49*BATCH*(EMB/4)+255)/256, 256, 0, stream>>>(trg, dec_emb, xd, 49);
    }

    dim3 xgrid(G4/128, 25);   // fallback grid

    // ---- encoder layer 0 Xp GEMM ----
    if (xp_ok)
        gemm_planes_gll<EMB, G4, 16><<<400, 256, 0, stream>>>(XAh, XAl, eW0h, eW0l, enc_b0, Xp, 3200);
    else
        gemm_mfma_split<EMB, G4><<<xgrid, 256, 0, stream>>>(xe, enc_Wih0, enc_b0, Xp, 3200);

    // ---- FUSED: encL0 LSTM + decL0-Xp GEMM (independent) ----
    if (xp_ok){
        lstm_gemm_k<<<656, 256, 0, stream>>>(
            Xp, enc_Whh0, hz, hz, eys0, c0, 50, flags + 0, XAh, XAl,
            Ahi, Alo, dW0h, dW0l, dec_b0, Xp2, 3136, 400);
    } else {
        lstm_layer_k<<<256, 256, 0, stream>>>(Xp, enc_Whh0, hz, hz, eys0, c0, 50, flags + 0,
                                              nullptr, nullptr);
        gemm_mfma_split<EMB, G4><<<xgrid, 256, 0, stream>>>(xd, dec_Wih0, dec_b0, Xp2, 3136);
    }

    // ---- encoder layer 1 Xp GEMM ----
    if (xp_ok)
        gemm_planes_gll<HID, G4, 16><<<400, 256, 0, stream>>>(XAh, XAl, eW1h, eW1l, enc_b1, Xp, 3200);
    else
        gemm_mfma_split<HID, G4><<<xgrid, 256, 0, stream>>>(eys0, enc_Wih1, enc_b1, Xp, 3200);

    // ---- encoder layer 1 AND decoder layer 0 concurrently ----
    lstm_dual_k<<<512, 256, 0, stream>>>(
        Xp,  enc_Whh1, hz,                          hz, eys1, c1, 50, flags + 4096,  nullptr, nullptr,
        Xp2, dec_Whh0, eys0 + (size_t)49*BATCH*HID, c0, dys0, c0, 49, flags + 8192,
        xp_ok ? XAh : nullptr, XAl);

    // ---- decoder layer 1 ----
    if (xp_ok)
        gemm_planes_gll<HID, G4, 16><<<400, 256, 0, stream>>>(XAh, XAl, dW1h, dW1l, dec_b1, Xp, 3136);
    else
        gemm_mfma_split<HID, G4><<<xgrid, 256, 0, stream>>>(dys0, dec_Wih1, dec_b1, Xp, 3136);
    lstm_layer_k<<<256, 256, 0, stream>>>(Xp, dec_Whh1, eys1 + (size_t)49*BATCH*HID, c1,
                                          dys1, c1, 49, flags + 12288,
                                          xp_ok ? Ahi : nullptr, Alo);

    // ---- final projection -> fp32 d_out [3136, 32000]: 1-pass bf16, 256x128 tile, 8 waves ----
    if (xp_ok){
        gemm_planes_256w8<HID, VOCAB, 250><<<13*250, 512, 0, stream>>>(
            Ahi, Whi, out_b, (float*)d_out, 3136);
    } else {
        gemm_mfma_split<HID, VOCAB><<<dim3(VOCAB/128, 25), 256, 0, stream>>>(
            dys1, out_W, out_b, (float*)d_out, 3136);
    }
}